// Round 1
// baseline (3517.775 us; speedup 1.0000x reference)
//
#include <hip/hip_runtime.h>
#include <math.h>

// Problem constants (fixed by the reference)
#define NN 50000      // nodes
#define NCH 4         // channels
#define NA 16         // attr dim
#define DOUT 64
#define KDIM 273      // A*A + 2*C + 9
#define OUTC 76       // 64 + 12

// ws layout (float offsets). All offsets divisible by 4 -> 16B aligned.
#define WT_OFF     0            // 273*64 = 17472 floats
#define LF_OFF     17472        // N*12
#define POOLED_OFF 617472       // N*4
#define CACC_OFF   817472       // N*12
#define CNT_OFF    1417472      // N
#define WS_FLOATS  1467472

// ---------------- W transpose: WT[k*64+d] = W[d*273+k] ----------------
__global__ void wt_kernel(const float* __restrict__ W, float* __restrict__ WT) {
    int t = blockIdx.x * blockDim.x + threadIdx.x;
    if (t >= KDIM * DOUT) return;
    int d = t & 63;
    int k = t >> 6;
    WT[t] = W[d * KDIM + k];
}

// ---------------- per-node: local frames + pooled means ----------------
__global__ void node_kernel(const float* __restrict__ coord,
                            const float* __restrict__ cw,
                            float* __restrict__ lf,
                            float* __restrict__ pooled) {
    int n = blockIdx.x * blockDim.x + threadIdx.x;
    if (n >= NN) return;
    const float* cp = coord + (size_t)n * 12;
    float c0x = cp[0], c0y = cp[1], c0z = cp[2];
    float c1x = cp[3], c1y = cp[4], c1z = cp[5];
    float c2x = cp[6], c2y = cp[7], c2z = cp[8];
    float c3x = cp[9], c3y = cp[10], c3z = cp[11];

    // x = normalize(c1 - c0)
    float xx = c1x - c0x, xy = c1y - c0y, xz = c1z - c0z;
    float invx = 1.0f / (sqrtf(xx * xx + xy * xy + xz * xz) + 1e-8f);
    xx *= invx; xy *= invx; xz *= invx;
    // y = normalize(t - (t.x)x), t = c2 - c0
    float tx = c2x - c0x, ty = c2y - c0y, tz = c2z - c0z;
    float dp = tx * xx + ty * xy + tz * xz;
    float yx = tx - dp * xx, yy = ty - dp * xy, yz = tz - dp * xz;
    float invy = 1.0f / (sqrtf(yx * yx + yy * yy + yz * yz) + 1e-8f);
    yx *= invy; yy *= invy; yz *= invy;
    // z = x cross y
    float zx = xy * yz - xz * yy;
    float zy = xz * yx - xx * yz;
    float zz = xx * yy - xy * yx;

    float* l = lf + (size_t)n * 12;
    // layout from stack([x,y,z], axis=-1).reshape(9): [x0,y0,z0,x1,y1,z1,x2,y2,z2]
    l[0] = xx; l[1] = yx; l[2] = zx;
    l[3] = xy; l[4] = yy; l[5] = zy;
    l[6] = xz; l[7] = yz; l[8] = zz;
    l[9] = 0.f; l[10] = 0.f; l[11] = 0.f;

    const float* w = cw + (size_t)n * 4;
    float m0 = (w[0] != 0.f) ? 1.f : 0.f;
    float m1 = (w[1] != 0.f) ? 1.f : 0.f;
    float m2 = (w[2] != 0.f) ? 1.f : 0.f;
    float m3 = (w[3] != 0.f) ? 1.f : 0.f;
    float cs = m0 + m1 + m2 + m3;   // ref divides directly (no clamp)
    float px = (c0x * m0 + c1x * m1 + c2x * m2 + c3x * m3) / cs;
    float py = (c0y * m0 + c1y * m1 + c2y * m2 + c3y * m3) / cs;
    float pz = (c0z * m0 + c1z * m1 + c2z * m2 + c3z * m3) / cs;
    float* p = pooled + (size_t)n * 4;
    p[0] = px; p[1] = py; p[2] = pz; p[3] = 0.f;
}

// ---------------- per-edge: radial -> W projection -> atomic aggregate ----------------
__global__ __launch_bounds__(256, 2) void edge_kernel(
    const float* __restrict__ coord, const float* __restrict__ attr,
    const float* __restrict__ cw, const float* __restrict__ WT,
    const float* __restrict__ bvec,
    const int* __restrict__ row, const int* __restrict__ col,
    const float* __restrict__ lf, const float* __restrict__ pooled,
    float* __restrict__ out, float* __restrict__ cacc, float* __restrict__ cnt,
    int E) {
    int e = blockIdx.x * blockDim.x + threadIdx.x;
    if (e >= E) return;
    int r = row[e];
    int c = col[e];

    // coords (12 floats each, 16B-aligned rows: 48B)
    float cr[12], cc_[12];
    const float4* c4 = (const float4*)coord;
    #pragma unroll
    for (int q = 0; q < 3; ++q) {
        float4 t = c4[(size_t)r * 3 + q];
        cr[q * 4 + 0] = t.x; cr[q * 4 + 1] = t.y; cr[q * 4 + 2] = t.z; cr[q * 4 + 3] = t.w;
    }
    #pragma unroll
    for (int q = 0; q < 3; ++q) {
        float4 t = c4[(size_t)c * 3 + q];
        cc_[q * 4 + 0] = t.x; cc_[q * 4 + 1] = t.y; cc_[q * 4 + 2] = t.z; cc_[q * 4 + 3] = t.w;
    }
    float4 wr4 = ((const float4*)cw)[r];
    float4 wc4 = ((const float4*)cw)[c];
    float wr[4] = {wr4.x, wr4.y, wr4.z, wr4.w};
    float wc[4] = {wc4.x, wc4.y, wc4.z, wc4.w};

    // M[i][j] = ||cr_i - cc_j|| * wr_i * wc_j
    float M[16];
    #pragma unroll
    for (int i = 0; i < 4; ++i) {
        #pragma unroll
        for (int j = 0; j < 4; ++j) {
            float dx = cr[i * 3 + 0] - cc_[j * 3 + 0];
            float dy = cr[i * 3 + 1] - cc_[j * 3 + 1];
            float dz = cr[i * 3 + 2] - cc_[j * 3 + 2];
            M[i * 4 + j] = sqrtf(dx * dx + dy * dy + dz * dz) * wr[i] * wc[j];
        }
    }

    // Ac = attr[c] (64 floats)
    float Ac[64];
    const float4* a4 = (const float4*)attr;
    #pragma unroll
    for (int q = 0; q < 16; ++q) {
        float4 v = a4[(size_t)c * 16 + q];
        Ac[q * 4 + 0] = v.x; Ac[q * 4 + 1] = v.y; Ac[q * 4 + 2] = v.z; Ac[q * 4 + 3] = v.w;
    }
    const float* Ar = attr + (size_t)r * 64;

    float acc[64];
    #pragma unroll
    for (int d = 0; d < 64; ++d) acc[d] = 0.f;
    float ssum = 0.f;

    // radial part: k = a*16 + b
    #pragma unroll 1
    for (int a = 0; a < 16; ++a) {
        float A0 = Ar[a], A1 = Ar[16 + a], A2 = Ar[32 + a], A3 = Ar[48 + a];
        float U[4];
        #pragma unroll
        for (int j = 0; j < 4; ++j)
            U[j] = A0 * M[j] + A1 * M[4 + j] + A2 * M[8 + j] + A3 * M[12 + j];
        const float* wbase = WT + a * 16 * 64;   // uniform address -> scalar loads
        #pragma unroll
        for (int bb = 0; bb < 16; ++bb) {
            float ek = U[0] * Ac[bb] + U[1] * Ac[16 + bb] + U[2] * Ac[32 + bb] + U[3] * Ac[48 + bb];
            ssum = fmaf(ek, ek, ssum);
            const float* wrow = wbase + bb * 64;
            #pragma unroll
            for (int d = 0; d < 64; ++d) acc[d] = fmaf(ek, wrow[d], acc[d]);
        }
    }

    // geo part: cols 256..263 are zeros (skipped); 264..272 = lf[r] + lf[c]
    const float* lr = lf + (size_t)r * 12;
    const float* lc = lf + (size_t)c * 12;
    const float* wl = WT + 264 * 64;
    #pragma unroll 1
    for (int t = 0; t < 9; ++t) {
        float v = lr[t] + lc[t];
        ssum = fmaf(v, v, ssum);
        const float* wrow = wl + t * 64;
        #pragma unroll
        for (int d = 0; d < 64; ++d) acc[d] = fmaf(v, wrow[d], acc[d]);
    }

    float invn = 1.0f / (sqrtf(ssum) + 1.0f);
    float* orow = out + (size_t)r * OUTC;
    #pragma unroll 1
    for (int d = 0; d < 64; ++d) atomicAdd(&orow[d], (acc[d] + bvec[d]) * invn);

    // coord aggregation: coord[row] - pooled[col], per channel
    float4 pc = ((const float4*)pooled)[c];
    float* ca = cacc + (size_t)r * 12;
    #pragma unroll
    for (int ch = 0; ch < 4; ++ch) {
        atomicAdd(&ca[ch * 3 + 0], cr[ch * 3 + 0] - pc.x);
        atomicAdd(&ca[ch * 3 + 1], cr[ch * 3 + 1] - pc.y);
        atomicAdd(&ca[ch * 3 + 2], cr[ch * 3 + 2] - pc.z);
    }
    atomicAdd(&cnt[r], 1.f);
}

// ---------------- per-node finalize: coord_agg / clip(cnt,1) ----------------
__global__ void final_kernel(const float* __restrict__ cacc,
                             const float* __restrict__ cnt,
                             float* __restrict__ out) {
    int n = blockIdx.x * blockDim.x + threadIdx.x;
    if (n >= NN) return;
    float inv = 1.0f / fmaxf(cnt[n], 1.0f);
    float* orow = out + (size_t)n * OUTC + 64;
    const float* ca = cacc + (size_t)n * 12;
    #pragma unroll
    for (int t = 0; t < 12; ++t) orow[t] = ca[t] * inv;
}

extern "C" void kernel_launch(void* const* d_in, const int* in_sizes, int n_in,
                              void* d_out, int out_size, void* d_ws, size_t ws_size,
                              hipStream_t stream) {
    const float* coord = (const float*)d_in[0];
    const float* attr  = (const float*)d_in[1];
    const float* cw    = (const float*)d_in[2];
    const float* W     = (const float*)d_in[3];
    const float* bvec  = (const float*)d_in[4];
    const int*   row   = (const int*)d_in[5];
    const int*   col   = (const int*)d_in[6];
    float* out = (float*)d_out;
    float* ws  = (float*)d_ws;
    int E = in_sizes[5];

    // zero the accumulators (d_out and ws are re-poisoned before every launch)
    hipMemsetAsync(out, 0, (size_t)NN * OUTC * sizeof(float), stream);
    hipMemsetAsync(ws + CACC_OFF, 0, (size_t)(NN * 12 + NN) * sizeof(float), stream);

    wt_kernel<<<(KDIM * DOUT + 255) / 256, 256, 0, stream>>>(W, ws + WT_OFF);
    node_kernel<<<(NN + 255) / 256, 256, 0, stream>>>(coord, cw, ws + LF_OFF, ws + POOLED_OFF);
    edge_kernel<<<(E + 255) / 256, 256, 0, stream>>>(
        coord, attr, cw, ws + WT_OFF, bvec, row, col,
        ws + LF_OFF, ws + POOLED_OFF, out, ws + CACC_OFF, ws + CNT_OFF, E);
    final_kernel<<<(NN + 255) / 256, 256, 0, stream>>>(ws + CACC_OFF, ws + CNT_OFF, out);
}

// Round 2
// 665.209 us; speedup vs baseline: 5.2882x; 5.2882x over previous
//
#include <hip/hip_runtime.h>
#include <math.h>

// Problem constants (fixed by the reference)
#define NN 50000      // nodes
#define EDG 800000    // edges
#define OUTC 76       // 64 + 12

// ws layout (4-byte units)
#define LF_OFF     0                        // NN*12 floats
#define POOLED_OFF (LF_OFF + NN*12)         // NN*4
#define WP_OFF     (POOLED_OFF + NN*4)      // 64*280 padded W
#define CNT_OFF    (WP_OFF + 64*280)        // NN ints (counts, then cursor)
#define OFFS_OFF   (CNT_OFF + NN)           // NN+1 ints (+3 pad)
#define EIDX_OFF   (OFFS_OFF + NN + 4)      // EDG ints
#define WS_UNITS   (EIDX_OFF + EDG)         // ~1.72M * 4B = 6.9 MB

// ---------------- W pad: Wp[d*280+k] = W[d*273+k], 0 beyond ----------------
__global__ void wp_kernel(const float* __restrict__ W, float* __restrict__ Wp) {
    int t = blockIdx.x * blockDim.x + threadIdx.x;
    if (t >= 64 * 280) return;
    int d = t / 280, k = t % 280;
    Wp[t] = (k < 273) ? W[d * 273 + k] : 0.f;
}

// ---------------- per-node: local frames + pooled means ----------------
__global__ void node_kernel(const float* __restrict__ coord,
                            const float* __restrict__ cw,
                            float* __restrict__ lf,
                            float* __restrict__ pooled) {
    int n = blockIdx.x * blockDim.x + threadIdx.x;
    if (n >= NN) return;
    const float* cp = coord + (size_t)n * 12;
    float c0x = cp[0], c0y = cp[1], c0z = cp[2];
    float c1x = cp[3], c1y = cp[4], c1z = cp[5];
    float c2x = cp[6], c2y = cp[7], c2z = cp[8];
    float c3x = cp[9], c3y = cp[10], c3z = cp[11];

    float xx = c1x - c0x, xy = c1y - c0y, xz = c1z - c0z;
    float invx = 1.0f / (sqrtf(xx * xx + xy * xy + xz * xz) + 1e-8f);
    xx *= invx; xy *= invx; xz *= invx;
    float tx = c2x - c0x, ty = c2y - c0y, tz = c2z - c0z;
    float dp = tx * xx + ty * xy + tz * xz;
    float yx = tx - dp * xx, yy = ty - dp * xy, yz = tz - dp * xz;
    float invy = 1.0f / (sqrtf(yx * yx + yy * yy + yz * yz) + 1e-8f);
    yx *= invy; yy *= invy; yz *= invy;
    float zx = xy * yz - xz * yy;
    float zy = xz * yx - xx * yz;
    float zz = xx * yy - xy * yx;

    float* l = lf + (size_t)n * 12;
    l[0] = xx; l[1] = yx; l[2] = zx;
    l[3] = xy; l[4] = yy; l[5] = zy;
    l[6] = xz; l[7] = yz; l[8] = zz;
    l[9] = 0.f; l[10] = 0.f; l[11] = 0.f;

    const float* w = cw + (size_t)n * 4;
    float m0 = (w[0] != 0.f) ? 1.f : 0.f;
    float m1 = (w[1] != 0.f) ? 1.f : 0.f;
    float m2 = (w[2] != 0.f) ? 1.f : 0.f;
    float m3 = (w[3] != 0.f) ? 1.f : 0.f;
    float cs = m0 + m1 + m2 + m3;   // ref divides directly (no clamp)
    float* p = pooled + (size_t)n * 4;
    p[0] = (c0x * m0 + c1x * m1 + c2x * m2 + c3x * m3) / cs;
    p[1] = (c0y * m0 + c1y * m1 + c2y * m2 + c3y * m3) / cs;
    p[2] = (c0z * m0 + c1z * m1 + c2z * m2 + c3z * m3) / cs;
    p[3] = 0.f;
}

// ---------------- CSR build ----------------
__global__ void hist_kernel(const int* __restrict__ row, int* __restrict__ counts, int E) {
    int e = blockIdx.x * blockDim.x + threadIdx.x;
    if (e < E) atomicAdd(&counts[row[e]], 1);
}

#define SCAN_T 1024
#define CHUNK 49
__global__ void scan_kernel(int* __restrict__ counts, int* __restrict__ offs) {
    __shared__ int part[SCAN_T];
    int t = threadIdx.x;
    int begin = t * CHUNK, end = min(begin + CHUNK, NN);
    int s = 0;
    for (int i = begin; i < end; ++i) s += counts[i];
    part[t] = s;
    __syncthreads();
    for (int d = 1; d < SCAN_T; d <<= 1) {
        int v = (t >= d) ? part[t - d] : 0;
        __syncthreads();
        part[t] += v;
        __syncthreads();
    }
    int base = part[t] - s;   // exclusive prefix
    for (int i = begin; i < end; ++i) {
        int cv = counts[i];
        offs[i] = base;
        base += cv;
        counts[i] = 0;        // becomes the scatter cursor
    }
    if (t == SCAN_T - 1) offs[NN] = base;
}

__global__ void scatter_kernel(const int* __restrict__ row, const int* __restrict__ offs,
                               int* __restrict__ cursor, int* __restrict__ eidx, int E) {
    int e = blockIdx.x * blockDim.x + threadIdx.x;
    if (e >= E) return;
    int r = row[e];
    int pos = offs[r] + atomicAdd(&cursor[r], 1);
    eidx[pos] = e;
}

// ---------------- main: one wave per node, fused projection ----------------
__global__ __launch_bounds__(256) void edge_kernel(
    const float* __restrict__ coord, const float* __restrict__ attr,
    const float* __restrict__ cw, const float* __restrict__ Wp,
    const float* __restrict__ bvec,
    const int* __restrict__ col,
    const float* __restrict__ lf, const float* __restrict__ pooled,
    const int* __restrict__ offs, const int* __restrict__ eidx,
    float* __restrict__ out) {
    __shared__ float Mbuf[4][16];
    __shared__ float Acbuf[4][64];
    __shared__ float S[4][272];

    int w = threadIdx.x >> 6;
    int l = threadIdx.x & 63;
    int n = blockIdx.x * 4 + w;

    int st = offs[n], en = offs[n + 1];

    // persistent per-lane state
    int a = l >> 2;              // attr dim a for this lane's 4 radial outputs
    int b0 = (l & 3) * 4;        // first b
    int i4 = (l >> 2) & 3;       // channel i for distance (lanes<16 meaningful)
    int j4 = l & 3;              // channel j for distance

    float ArA0 = attr[n * 64 + 0 * 16 + a];
    float ArA1 = attr[n * 64 + 1 * 16 + a];
    float ArA2 = attr[n * 64 + 2 * 16 + a];
    float ArA3 = attr[n * 64 + 3 * 16 + a];
    float crx = coord[n * 12 + i4 * 3 + 0];
    float cry = coord[n * 12 + i4 * 3 + 1];
    float crz = coord[n * 12 + i4 * 3 + 2];
    float cwr = cw[n * 4 + i4];
    float lrv = (l < 9) ? lf[n * 12 + l] : 0.f;

    float ax = 0.f, ay = 0.f, az = 0.f, aw = 0.f;   // 4 radial accumulators
    float sgeo = 0.f, invs = 0.f, sp = 0.f;

    for (int i = st; i < en; ++i) {
        int eid = eidx[i];
        int c = col[eid];
        // independent per-lane gathers (L2/L3 resident)
        float ccx = coord[c * 12 + j4 * 3 + 0];
        float ccy = coord[c * 12 + j4 * 3 + 1];
        float ccz = coord[c * 12 + j4 * 3 + 2];
        float cwc = cw[c * 4 + j4];
        float acv = attr[c * 64 + l];
        float lcv = (l < 9) ? lf[c * 12 + l] : 0.f;
        float pv  = (l < 3) ? pooled[c * 4 + l] : 0.f;

        float dx = crx - ccx, dy = cry - ccy, dz = crz - ccz;
        float m = sqrtf(dx * dx + dy * dy + dz * dz) * cwr * cwc;
        if (l < 16) Mbuf[w][l] = m;       // M[i][j] at i*4+j
        Acbuf[w][l] = acv;                // attr[c] row
        // intra-wave LDS RAW: DS ops issue in order per wave; compiler keeps
        // may-alias LDS accesses ordered.
        float4 M0 = *(const float4*)&Mbuf[w][0];
        float4 M1 = *(const float4*)&Mbuf[w][4];
        float4 M2 = *(const float4*)&Mbuf[w][8];
        float4 M3 = *(const float4*)&Mbuf[w][12];
        // U[j] = sum_i Ar[i][a] * M[i][j]
        float Ux = ArA0 * M0.x + ArA1 * M1.x + ArA2 * M2.x + ArA3 * M3.x;
        float Uy = ArA0 * M0.y + ArA1 * M1.y + ArA2 * M2.y + ArA3 * M3.y;
        float Uz = ArA0 * M0.z + ArA1 * M1.z + ArA2 * M2.z + ArA3 * M3.z;
        float Uw = ArA0 * M0.w + ArA1 * M1.w + ArA2 * M2.w + ArA3 * M3.w;
        float4 A0 = *(const float4*)&Acbuf[w][0 * 16 + b0];
        float4 A1 = *(const float4*)&Acbuf[w][1 * 16 + b0];
        float4 A2 = *(const float4*)&Acbuf[w][2 * 16 + b0];
        float4 A3 = *(const float4*)&Acbuf[w][3 * 16 + b0];
        // e_k = sum_j U[j] * Ac[j][b]
        float ex = Ux * A0.x + Uy * A1.x + Uz * A2.x + Uw * A3.x;
        float ey = Ux * A0.y + Uy * A1.y + Uz * A2.y + Uw * A3.y;
        float ez = Ux * A0.z + Uy * A1.z + Uz * A2.z + Uw * A3.z;
        float ew = Ux * A0.w + Uy * A1.w + Uz * A2.w + Uw * A3.w;

        float glf = lrv + lcv;
        float ls = ex * ex + ey * ey + ez * ez + ew * ew + glf * glf;
        #pragma unroll
        for (int o = 1; o < 64; o <<= 1) ls += __shfl_xor(ls, o);
        float invr = 1.f / (sqrtf(ls) + 1.f);

        ax += ex * invr; ay += ey * invr; az += ez * invr; aw += ew * invr;
        sgeo += glf * invr;
        invs += invr;
        sp += pv;
    }

    // stash per-node sums in LDS (this wave's own slot)
    *(float4*)&S[w][l * 4] = make_float4(ax, ay, az, aw);   // radial k = l*4+m
    if (l < 9)  S[w][256 + l] = sgeo;
    if (l == 0) S[w][265] = invs;
    if (l < 3)  S[w][266 + l] = sp;
    if (l == 10) S[w][269] = (float)(en - st);
    __syncthreads();

    // projection: out[n][d] = b[d]*invsum + sum_k s[k]*W[d][k]
    float invsum = S[w][265];
    float acc = bvec[l] * invsum;
    const float4* wrow = (const float4*)(Wp + l * 280);
    #pragma unroll 8
    for (int q = 0; q < 64; ++q) {
        float4 w4 = wrow[q];
        float4 s4 = *(const float4*)&S[w][q * 4];
        acc += w4.x * s4.x + w4.y * s4.y + w4.z * s4.z + w4.w * s4.w;
    }
    const float* wg = Wp + l * 280 + 264;
    #pragma unroll
    for (int t = 0; t < 9; ++t) acc += S[w][256 + t] * wg[t];
    out[(size_t)n * OUTC + l] = acc;

    // coord_agg: (cnt*coord[n] - sum pooled[c]) / max(cnt,1)
    float cntv = S[w][269];
    float invc = 1.f / fmaxf(cntv, 1.f);
    if (l < 12) {
        int x = l % 3;
        out[(size_t)n * OUTC + 64 + l] = (cntv * coord[n * 12 + l] - S[w][266 + x]) * invc;
    }
}

extern "C" void kernel_launch(void* const* d_in, const int* in_sizes, int n_in,
                              void* d_out, int out_size, void* d_ws, size_t ws_size,
                              hipStream_t stream) {
    const float* coord = (const float*)d_in[0];
    const float* attr  = (const float*)d_in[1];
    const float* cw    = (const float*)d_in[2];
    const float* W     = (const float*)d_in[3];
    const float* bvec  = (const float*)d_in[4];
    const int*   row   = (const int*)d_in[5];
    const int*   col   = (const int*)d_in[6];
    float* out = (float*)d_out;
    float* ws  = (float*)d_ws;
    int E = in_sizes[5];

    float* lf     = ws + LF_OFF;
    float* pooled = ws + POOLED_OFF;
    float* Wp     = ws + WP_OFF;
    int*   counts = (int*)(ws + CNT_OFF);
    int*   offs   = (int*)(ws + OFFS_OFF);
    int*   eidx   = (int*)(ws + EIDX_OFF);

    hipMemsetAsync(counts, 0, NN * sizeof(int), stream);
    wp_kernel<<<(64 * 280 + 255) / 256, 256, 0, stream>>>(W, Wp);
    node_kernel<<<(NN + 255) / 256, 256, 0, stream>>>(coord, cw, lf, pooled);
    hist_kernel<<<(E + 255) / 256, 256, 0, stream>>>(row, counts, E);
    scan_kernel<<<1, SCAN_T, 0, stream>>>(counts, offs);
    scatter_kernel<<<(E + 255) / 256, 256, 0, stream>>>(row, offs, counts, eidx, E);
    edge_kernel<<<NN / 4, 256, 0, stream>>>(coord, attr, cw, Wp, bvec, col,
                                            lf, pooled, offs, eidx, out);
}

// Round 3
// 407.789 us; speedup vs baseline: 8.6265x; 1.6313x over previous
//
#include <hip/hip_runtime.h>
#include <math.h>

// Problem constants (fixed by the reference)
#define NN 50000
#define EDG 800000
#define OUTC 76
#define NKB 68          // 272/4 k-blocks in the packed-W projection

// ws float offsets
#define CCW_OFF  0                     // NN*16  packed (xyz,cw) per channel
#define LFP_OFF  (CCW_OFF + NN*16)     // NN*16  [lf*9, 0,0,0, pooled*3, 0]
#define WK_OFF   (LFP_OFF + NN*16)     // NKB*256 k-major packed W
#define CNT_OFF  (WK_OFF + NKB*256)    // NN ints
#define OFFS_OFF (CNT_OFF + NN)        // NN+1 ints (+pad)
#define PERM_OFF (OFFS_OFF + NN + 4)   // EDG ints
#define ECOL_OFF (PERM_OFF + EDG)      // EDG ints
// total ~3.32M floats = 13.3 MB

// ---------------- prep: packed inputs + local frames + pooled + WK ----------
__global__ void prep_kernel(const float* __restrict__ coord,
                            const float* __restrict__ cw,
                            const float* __restrict__ W,
                            float* __restrict__ ccwp,
                            float* __restrict__ lfp,
                            float* __restrict__ wk) {
    int t = blockIdx.x * blockDim.x + threadIdx.x;

    // WK[kb][d][km] = W[d][kcol(kb*4+km)], zero for dead columns.
    // effective k: 0..255 -> W col k (radial); 256..264 -> W col k+8 (geo); else 0
    if (t < NKB * 64) {
        int kb = t >> 6, d = t & 63;
        float tmp[4];
        #pragma unroll
        for (int km = 0; km < 4; ++km) {
            int k = kb * 4 + km;
            int kcol = (k < 256) ? k : ((k < 265) ? k + 8 : -1);
            tmp[km] = (kcol >= 0) ? W[d * 273 + kcol] : 0.f;
        }
        ((float4*)wk)[t] = make_float4(tmp[0], tmp[1], tmp[2], tmp[3]);
    }

    if (t >= NN) return;
    const float* cp = coord + (size_t)t * 12;
    float c0x = cp[0], c0y = cp[1], c0z = cp[2];
    float c1x = cp[3], c1y = cp[4], c1z = cp[5];
    float c2x = cp[6], c2y = cp[7], c2z = cp[8];
    float c3x = cp[9], c3y = cp[10], c3z = cp[11];
    const float* wv = cw + (size_t)t * 4;
    float w0 = wv[0], w1 = wv[1], w2 = wv[2], w3 = wv[3];

    // packed coord+cw row
    float* cc = ccwp + (size_t)t * 16;
    cc[0] = c0x; cc[1] = c0y; cc[2] = c0z; cc[3] = w0;
    cc[4] = c1x; cc[5] = c1y; cc[6] = c1z; cc[7] = w1;
    cc[8] = c2x; cc[9] = c2y; cc[10] = c2z; cc[11] = w2;
    cc[12] = c3x; cc[13] = c3y; cc[14] = c3z; cc[15] = w3;

    // local frame
    float xx = c1x - c0x, xy = c1y - c0y, xz = c1z - c0z;
    float invx = 1.0f / (sqrtf(xx * xx + xy * xy + xz * xz) + 1e-8f);
    xx *= invx; xy *= invx; xz *= invx;
    float tx = c2x - c0x, ty = c2y - c0y, tz = c2z - c0z;
    float dp = tx * xx + ty * xy + tz * xz;
    float yx = tx - dp * xx, yy = ty - dp * xy, yz = tz - dp * xz;
    float invy = 1.0f / (sqrtf(yx * yx + yy * yy + yz * yz) + 1e-8f);
    yx *= invy; yy *= invy; yz *= invy;
    float zx = xy * yz - xz * yy;
    float zy = xz * yx - xx * yz;
    float zz = xx * yy - xy * yx;

    // pooled mean
    float m0 = (w0 != 0.f) ? 1.f : 0.f;
    float m1 = (w1 != 0.f) ? 1.f : 0.f;
    float m2 = (w2 != 0.f) ? 1.f : 0.f;
    float m3 = (w3 != 0.f) ? 1.f : 0.f;
    float cs = m0 + m1 + m2 + m3;      // ref divides directly (no clamp)
    float px = (c0x * m0 + c1x * m1 + c2x * m2 + c3x * m3) / cs;
    float py = (c0y * m0 + c1y * m1 + c2y * m2 + c3y * m3) / cs;
    float pz = (c0z * m0 + c1z * m1 + c2z * m2 + c3z * m3) / cs;

    float* lp = lfp + (size_t)t * 16;
    lp[0] = xx; lp[1] = yx; lp[2] = zx;
    lp[3] = xy; lp[4] = yy; lp[5] = zy;
    lp[6] = xz; lp[7] = yz; lp[8] = zz;
    lp[9] = 0.f; lp[10] = 0.f; lp[11] = 0.f;
    lp[12] = px; lp[13] = py; lp[14] = pz; lp[15] = 0.f;
}

// ---------------- CSR build ----------------
__global__ void hist_kernel(const int* __restrict__ row, int* __restrict__ counts,
                            int* __restrict__ perm, int E) {
    int e = blockIdx.x * blockDim.x + threadIdx.x;
    if (e < E) perm[e] = atomicAdd(&counts[row[e]], 1);
}

#define SCAN_T 1024
#define CHUNK 49
__global__ void scan_kernel(const int* __restrict__ counts, int* __restrict__ offs) {
    __shared__ int part[SCAN_T];
    int t = threadIdx.x;
    int begin = t * CHUNK, end = min(begin + CHUNK, NN);
    int s = 0;
    for (int i = begin; i < end; ++i) s += counts[i];
    part[t] = s;
    __syncthreads();
    for (int d = 1; d < SCAN_T; d <<= 1) {
        int v = (t >= d) ? part[t - d] : 0;
        __syncthreads();
        part[t] += v;
        __syncthreads();
    }
    int base = part[t] - s;   // exclusive prefix
    for (int i = begin; i < end; ++i) {
        offs[i] = base;
        base += counts[i];
    }
    if (t == SCAN_T - 1) offs[NN] = base;
}

__global__ void scatter_kernel(const int* __restrict__ row, const int* __restrict__ col,
                               const int* __restrict__ offs, const int* __restrict__ perm,
                               int* __restrict__ ecol, int E) {
    int e = blockIdx.x * blockDim.x + threadIdx.x;
    if (e >= E) return;
    ecol[offs[row[e]] + perm[e]] = col[e];
}

// ---------------- DPP wave-64 sum (rocPRIM-style ladder) ----------------
__device__ __forceinline__ float wave_sum64(float x) {
    float v = x, t;
    t = __int_as_float(__builtin_amdgcn_update_dpp(0, __float_as_int(v), 0x111, 0xf, 0xf, true)); v += t; // row_shr:1
    t = __int_as_float(__builtin_amdgcn_update_dpp(0, __float_as_int(v), 0x112, 0xf, 0xf, true)); v += t; // row_shr:2
    t = __int_as_float(__builtin_amdgcn_update_dpp(0, __float_as_int(v), 0x114, 0xf, 0xf, true)); v += t; // row_shr:4
    t = __int_as_float(__builtin_amdgcn_update_dpp(0, __float_as_int(v), 0x118, 0xf, 0xf, true)); v += t; // row_shr:8
    t = __int_as_float(__builtin_amdgcn_update_dpp(0, __float_as_int(v), 0x142, 0xa, 0xf, true)); v += t; // row_bcast:15
    t = __int_as_float(__builtin_amdgcn_update_dpp(0, __float_as_int(v), 0x143, 0xc, 0xf, true)); v += t; // row_bcast:31
    return __int_as_float(__builtin_amdgcn_readlane(__float_as_int(v), 63));
}

// ---------------- main: one wave per node ----------------
__global__ __launch_bounds__(256) void edge_kernel(
    const float* __restrict__ coord, const float* __restrict__ attr,
    const float* __restrict__ bvec,
    const float* __restrict__ ccw, const float* __restrict__ lfp,
    const float* __restrict__ wk,
    const int* __restrict__ offs, const int* __restrict__ ecol,
    float* __restrict__ out) {
    __shared__ float Mbuf[4][64];   // lanes 16+ write replicas; reads use [0..15]
    __shared__ float Acbuf[4][64];
    __shared__ float S[4][280];

    const int w = threadIdx.x >> 6;
    const int l = threadIdx.x & 63;
    const int n = blockIdx.x * 4 + w;

    const int st = offs[n], en = offs[n + 1];
    const int b0 = (l & 3) * 4;
    const int i4 = (l >> 2) & 3;
    const int j4 = l & 3;
    const int a  = l >> 2;

    const float ArA0 = attr[(size_t)n * 64 + 0 * 16 + a];
    const float ArA1 = attr[(size_t)n * 64 + 1 * 16 + a];
    const float ArA2 = attr[(size_t)n * 64 + 2 * 16 + a];
    const float ArA3 = attr[(size_t)n * 64 + 3 * 16 + a];
    const float4 cown = ((const float4*)ccw)[n * 4 + i4];
    const float crx = cown.x, cry = cown.y, crz = cown.z, cwr = cown.w;
    const float lrv = lfp[(size_t)n * 16 + l];
    const float lfmask = (l < 9) ? 1.f : 0.f;
    const float pmask  = (l >= 12 && l < 15) ? 1.f : 0.f;

    float ax = 0.f, ay = 0.f, az = 0.f, aw = 0.f;
    float sgeo = 0.f, invs = 0.f, sp = 0.f;

    const float4* CCW4 = (const float4*)ccw;

    for (int base = st; base < en; base += 64) {
        int bcnt = en - base; bcnt = bcnt > 64 ? 64 : bcnt;
        int idx = base + (l < bcnt ? l : bcnt - 1);
        int cvec = ecol[idx];                      // whole adjacency batch in one load

        int c = __builtin_amdgcn_readlane(cvec, 0);  // SGPR -> scalar addr math
        float4 cc  = CCW4[c * 4 + j4];
        float  acv = attr[(size_t)c * 64 + l];
        float  lcv = lfp[c * 16 + l];

        for (int k = 0; k < bcnt; ++k) {
            // issue next edge's gathers early (latency hides under compute)
            int kn = (k + 1 < bcnt) ? k + 1 : k;
            int c2 = __builtin_amdgcn_readlane(cvec, kn);
            float4 cc_n  = CCW4[c2 * 4 + j4];
            float  ac_n  = attr[(size_t)c2 * 64 + l];
            float  lcv_n = lfp[c2 * 16 + l];

            // distance matrix entry (each 16-lane quarter computes the same 16)
            float dx = crx - cc.x, dy = cry - cc.y, dz = crz - cc.z;
            float m = __builtin_amdgcn_sqrtf(dx * dx + dy * dy + dz * dz) * cwr * cc.w;
            Mbuf[w][l]  = m;
            Acbuf[w][l] = acv;
            float4 M0 = *(const float4*)&Mbuf[w][0];
            float4 M1 = *(const float4*)&Mbuf[w][4];
            float4 M2 = *(const float4*)&Mbuf[w][8];
            float4 M3 = *(const float4*)&Mbuf[w][12];
            float Ux = ArA0 * M0.x + ArA1 * M1.x + ArA2 * M2.x + ArA3 * M3.x;
            float Uy = ArA0 * M0.y + ArA1 * M1.y + ArA2 * M2.y + ArA3 * M3.y;
            float Uz = ArA0 * M0.z + ArA1 * M1.z + ArA2 * M2.z + ArA3 * M3.z;
            float Uw = ArA0 * M0.w + ArA1 * M1.w + ArA2 * M2.w + ArA3 * M3.w;
            float4 A0 = *(const float4*)&Acbuf[w][b0];
            float4 A1 = *(const float4*)&Acbuf[w][16 + b0];
            float4 A2 = *(const float4*)&Acbuf[w][32 + b0];
            float4 A3 = *(const float4*)&Acbuf[w][48 + b0];
            float ex = Ux * A0.x + Uy * A1.x + Uz * A2.x + Uw * A3.x;
            float ey = Ux * A0.y + Uy * A1.y + Uz * A2.y + Uw * A3.y;
            float ez = Ux * A0.z + Uy * A1.z + Uz * A2.z + Uw * A3.z;
            float ew = Ux * A0.w + Uy * A1.w + Uz * A2.w + Uw * A3.w;

            float glf  = (lrv + lcv) * lfmask;
            float part = ex * ex + ey * ey + ez * ez + ew * ew + glf * glf;
            float tot  = wave_sum64(part);
            float invr = __builtin_amdgcn_rcpf(__builtin_amdgcn_sqrtf(tot) + 1.f);

            ax = fmaf(ex, invr, ax); ay = fmaf(ey, invr, ay);
            az = fmaf(ez, invr, az); aw = fmaf(ew, invr, aw);
            sgeo = fmaf(glf, invr, sgeo);
            invs += invr;
            sp = fmaf(lcv, pmask, sp);

            cc = cc_n; acv = ac_n; lcv = lcv_n;
        }
    }

    // stash per-node sums: [0..255] radial (k = l*4+m == a*16+b), [256..264] geo,
    // [265..271] zero-pad, [272] invs, [273..275] pooled sums, [276] cnt
    *(float4*)&S[w][l * 4] = make_float4(ax, ay, az, aw);
    if (l < 9)       S[w][256 + l] = sgeo;
    else if (l < 16) S[w][256 + l] = 0.f;
    if (l == 16)     S[w][272] = invs;
    if (l >= 12 && l < 15) S[w][273 + (l - 12)] = sp;
    if (l == 17)     S[w][276] = (float)(en - st);
    __syncthreads();

    // coalesced projection: lane l = output dim d
    float invsum = S[w][272];
    float acc = bvec[l] * invsum;
    const float4* WK4 = (const float4*)wk;
    #pragma unroll 4
    for (int kb = 0; kb < NKB; ++kb) {
        float4 wv = WK4[kb * 64 + l];                 // 1 KB contiguous per wave
        float4 sv = *(const float4*)&S[w][kb * 4];    // broadcast
        acc += wv.x * sv.x + wv.y * sv.y + wv.z * sv.z + wv.w * sv.w;
    }
    out[(size_t)n * OUTC + l] = acc;

    float cntv = S[w][276];
    float invc = __builtin_amdgcn_rcpf(fmaxf(cntv, 1.f));
    if (l < 12) {
        int x = l % 3;
        out[(size_t)n * OUTC + 64 + l] = (cntv * coord[(size_t)n * 12 + l] - S[w][273 + x]) * invc;
    }
}

extern "C" void kernel_launch(void* const* d_in, const int* in_sizes, int n_in,
                              void* d_out, int out_size, void* d_ws, size_t ws_size,
                              hipStream_t stream) {
    const float* coord = (const float*)d_in[0];
    const float* attr  = (const float*)d_in[1];
    const float* cw    = (const float*)d_in[2];
    const float* W     = (const float*)d_in[3];
    const float* bvec  = (const float*)d_in[4];
    const int*   row   = (const int*)d_in[5];
    const int*   col   = (const int*)d_in[6];
    float* out = (float*)d_out;
    float* ws  = (float*)d_ws;
    int E = in_sizes[5];

    float* ccwp = ws + CCW_OFF;
    float* lfp  = ws + LFP_OFF;
    float* wk   = ws + WK_OFF;
    int* counts = (int*)(ws + CNT_OFF);
    int* offs   = (int*)(ws + OFFS_OFF);
    int* perm   = (int*)(ws + PERM_OFF);
    int* ecol   = (int*)(ws + ECOL_OFF);

    hipMemsetAsync(counts, 0, NN * sizeof(int), stream);
    prep_kernel<<<(NN + 255) / 256, 256, 0, stream>>>(coord, cw, W, ccwp, lfp, wk);
    hist_kernel<<<(E + 255) / 256, 256, 0, stream>>>(row, counts, perm, E);
    scan_kernel<<<1, SCAN_T, 0, stream>>>(counts, offs);
    scatter_kernel<<<(E + 255) / 256, 256, 0, stream>>>(row, col, offs, perm, ecol, E);
    edge_kernel<<<NN / 4, 256, 0, stream>>>(coord, attr, bvec, ccwp, lfp, wk,
                                            offs, ecol, out);
}

// Round 5
// 324.562 us; speedup vs baseline: 10.8385x; 1.2564x over previous
//
#include <hip/hip_runtime.h>
#include <math.h>

// Problem constants (fixed by the reference)
#define NN 50000
#define EDG 800000
#define OUTC 76
#define NKB 68          // 272/4 k-blocks in the packed-W projection
#define NB  196         // scan blocks = ceil(NN/256)

// ws float offsets
#define CCW_OFF  0                     // NN*16  packed (xyz,cw) per channel
#define LFP_OFF  (CCW_OFF + NN*16)     // NN*16  [lf*9, 0,0,0, pooled*3, 0]
#define WK_OFF   (LFP_OFF + NN*16)     // NKB*256 k-major packed W
#define CNT_OFF  (WK_OFF + NKB*256)    // NN ints
#define OFFS_OFF (CNT_OFF + NN)        // NN+1 ints (+pad)
#define PERM_OFF (OFFS_OFF + NN + 4)   // EDG ints
#define ECOL_OFF (PERM_OFF + EDG)      // EDG ints
#define BSUM_OFF (ECOL_OFF + EDG)      // NB ints (+pad)
// total ~3.32M floats = 13.3 MB

// ---------------- prep: packed inputs + local frames + pooled + WK ----------
__global__ void prep_kernel(const float* __restrict__ coord,
                            const float* __restrict__ cw,
                            const float* __restrict__ W,
                            float* __restrict__ ccwp,
                            float* __restrict__ lfp,
                            float* __restrict__ wk) {
    int t = blockIdx.x * blockDim.x + threadIdx.x;

    // WK[kb][d][km] = W[d][kcol(kb*4+km)], zero for dead columns.
    if (t < NKB * 64) {
        int kb = t >> 6, d = t & 63;
        float tmp[4];
        #pragma unroll
        for (int km = 0; km < 4; ++km) {
            int k = kb * 4 + km;
            int kcol = (k < 256) ? k : ((k < 265) ? k + 8 : -1);
            tmp[km] = (kcol >= 0) ? W[d * 273 + kcol] : 0.f;
        }
        ((float4*)wk)[t] = make_float4(tmp[0], tmp[1], tmp[2], tmp[3]);
    }

    if (t >= NN) return;
    const float* cp = coord + (size_t)t * 12;
    float c0x = cp[0], c0y = cp[1], c0z = cp[2];
    float c1x = cp[3], c1y = cp[4], c1z = cp[5];
    float c2x = cp[6], c2y = cp[7], c2z = cp[8];
    float c3x = cp[9], c3y = cp[10], c3z = cp[11];
    const float* wv = cw + (size_t)t * 4;
    float w0 = wv[0], w1 = wv[1], w2 = wv[2], w3 = wv[3];

    float* cc = ccwp + (size_t)t * 16;
    cc[0] = c0x; cc[1] = c0y; cc[2] = c0z; cc[3] = w0;
    cc[4] = c1x; cc[5] = c1y; cc[6] = c1z; cc[7] = w1;
    cc[8] = c2x; cc[9] = c2y; cc[10] = c2z; cc[11] = w2;
    cc[12] = c3x; cc[13] = c3y; cc[14] = c3z; cc[15] = w3;

    float xx = c1x - c0x, xy = c1y - c0y, xz = c1z - c0z;
    float invx = 1.0f / (sqrtf(xx * xx + xy * xy + xz * xz) + 1e-8f);
    xx *= invx; xy *= invx; xz *= invx;
    float tx = c2x - c0x, ty = c2y - c0y, tz = c2z - c0z;
    float dp = tx * xx + ty * xy + tz * xz;
    float yx = tx - dp * xx, yy = ty - dp * xy, yz = tz - dp * xz;
    float invy = 1.0f / (sqrtf(yx * yx + yy * yy + yz * yz) + 1e-8f);
    yx *= invy; yy *= invy; yz *= invy;
    float zx = xy * yz - xz * yy;
    float zy = xz * yx - xx * yz;
    float zz = xx * yy - xy * yx;

    float m0 = (w0 != 0.f) ? 1.f : 0.f;
    float m1 = (w1 != 0.f) ? 1.f : 0.f;
    float m2 = (w2 != 0.f) ? 1.f : 0.f;
    float m3 = (w3 != 0.f) ? 1.f : 0.f;
    float cs = m0 + m1 + m2 + m3;      // ref divides directly (no clamp)
    float px = (c0x * m0 + c1x * m1 + c2x * m2 + c3x * m3) / cs;
    float py = (c0y * m0 + c1y * m1 + c2y * m2 + c3y * m3) / cs;
    float pz = (c0z * m0 + c1z * m1 + c2z * m2 + c3z * m3) / cs;

    float* lp = lfp + (size_t)t * 16;
    lp[0] = xx; lp[1] = yx; lp[2] = zx;
    lp[3] = xy; lp[4] = yy; lp[5] = zy;
    lp[6] = xz; lp[7] = yz; lp[8] = zz;
    lp[9] = 0.f; lp[10] = 0.f; lp[11] = 0.f;
    lp[12] = px; lp[13] = py; lp[14] = pz; lp[15] = 0.f;
}

// ---------------- CSR build ----------------
__global__ void hist_kernel(const int* __restrict__ row, int* __restrict__ counts,
                            int* __restrict__ perm, int E) {
    int e = blockIdx.x * blockDim.x + threadIdx.x;
    if (e < E) perm[e] = atomicAdd(&counts[row[e]], 1);
}

// scan phase 1: per-block sums (coalesced)
__global__ void scan1_kernel(const int* __restrict__ counts, int* __restrict__ bsum) {
    int t = blockIdx.x * 256 + threadIdx.x;
    int v = (t < NN) ? counts[t] : 0;
    #pragma unroll
    for (int d = 1; d < 64; d <<= 1) v += __shfl_xor(v, d);
    __shared__ int wsum[4];
    int wid = threadIdx.x >> 6, lane = threadIdx.x & 63;
    if (lane == 0) wsum[wid] = v;
    __syncthreads();
    if (threadIdx.x == 0) bsum[blockIdx.x] = wsum[0] + wsum[1] + wsum[2] + wsum[3];
}

// scan phase 2: exclusive-scan the NB block sums (single block)
__global__ void scan2_kernel(int* __restrict__ bsum, int* __restrict__ offs) {
    __shared__ int sh[256];
    int t = threadIdx.x;
    int v = (t < NB) ? bsum[t] : 0;
    sh[t] = v;
    __syncthreads();
    for (int d = 1; d < 256; d <<= 1) {
        int u = (t >= d) ? sh[t - d] : 0;
        __syncthreads();
        sh[t] += u;
        __syncthreads();
    }
    if (t < NB) bsum[t] = sh[t] - v;      // exclusive block base
    if (t == NB - 1) offs[NN] = sh[t];    // total = E
}

// scan phase 3: block-local exclusive scan + block base
__global__ void scan3_kernel(const int* __restrict__ counts, const int* __restrict__ bsum,
                             int* __restrict__ offs) {
    int t = blockIdx.x * 256 + threadIdx.x;
    int v = (t < NN) ? counts[t] : 0;
    int lane = threadIdx.x & 63, wid = threadIdx.x >> 6;
    int x = v;
    #pragma unroll
    for (int d = 1; d < 64; d <<= 1) {
        int u = __shfl_up(x, d);
        x += (lane >= d) ? u : 0;
    }
    __shared__ int wtot[4];
    if (lane == 63) wtot[wid] = x;
    __syncthreads();
    int wbase = 0;
    for (int i = 0; i < wid; ++i) wbase += wtot[i];
    if (t < NN) offs[t] = bsum[blockIdx.x] + wbase + x - v;
}

__global__ void scatter_kernel(const int* __restrict__ row, const int* __restrict__ col,
                               const int* __restrict__ offs, const int* __restrict__ perm,
                               int* __restrict__ ecol, int E) {
    int e = blockIdx.x * blockDim.x + threadIdx.x;
    if (e >= E) return;
    ecol[offs[row[e]] + perm[e]] = col[e];
}

// ---------------- DPP wave-64 sum ----------------
__device__ __forceinline__ float wave_sum64(float x) {
    float v = x, t;
    t = __int_as_float(__builtin_amdgcn_update_dpp(0, __float_as_int(v), 0x111, 0xf, 0xf, true)); v += t;
    t = __int_as_float(__builtin_amdgcn_update_dpp(0, __float_as_int(v), 0x112, 0xf, 0xf, true)); v += t;
    t = __int_as_float(__builtin_amdgcn_update_dpp(0, __float_as_int(v), 0x114, 0xf, 0xf, true)); v += t;
    t = __int_as_float(__builtin_amdgcn_update_dpp(0, __float_as_int(v), 0x118, 0xf, 0xf, true)); v += t;
    t = __int_as_float(__builtin_amdgcn_update_dpp(0, __float_as_int(v), 0x142, 0xa, 0xf, true)); v += t;
    t = __int_as_float(__builtin_amdgcn_update_dpp(0, __float_as_int(v), 0x143, 0xc, 0xf, true)); v += t;
    return __int_as_float(__builtin_amdgcn_readlane(__float_as_int(v), 63));
}

#define RLF(v, k) __int_as_float(__builtin_amdgcn_readlane(__float_as_int(v), k))

// ---------------- main: one wave per node ----------------
__global__ __launch_bounds__(256) void edge_kernel(
    const float* __restrict__ coord, const float* __restrict__ attr,
    const float* __restrict__ bvec,
    const float* __restrict__ ccw, const float* __restrict__ lfp,
    const float* __restrict__ wk,
    const int* __restrict__ offs, const int* __restrict__ ecol,
    float* __restrict__ out) {
    __shared__ float Acbuf[4][64];
    __shared__ float S[4][280];

    const int w = threadIdx.x >> 6;
    const int l = threadIdx.x & 63;
    const int n = blockIdx.x * 4 + w;

    const int st = offs[n], en = offs[n + 1];
    const int b0 = (l & 3) * 4;
    const int i4 = (l >> 2) & 3;
    const int j4 = l & 3;
    const int a  = l >> 2;

    const float ArA0 = attr[(size_t)n * 64 + 0 * 16 + a];
    const float ArA1 = attr[(size_t)n * 64 + 1 * 16 + a];
    const float ArA2 = attr[(size_t)n * 64 + 2 * 16 + a];
    const float ArA3 = attr[(size_t)n * 64 + 3 * 16 + a];
    const float4 cown = ((const float4*)ccw)[n * 4 + i4];
    const float crx = cown.x, cry = cown.y, crz = cown.z, cwr = cown.w;
    const float lrv = lfp[(size_t)n * 16 + l];
    const float lfmask = (l < 9) ? 1.f : 0.f;
    const float pmask  = (l >= 12 && l < 15) ? 1.f : 0.f;

    float ax = 0.f, ay = 0.f, az = 0.f, aw = 0.f;
    float sgeo = 0.f, invs = 0.f, sp = 0.f;

    const float4* CCW4 = (const float4*)ccw;

    for (int base = st; base < en; base += 64) {
        int bcnt = en - base; bcnt = bcnt > 64 ? 64 : bcnt;
        int idx = base + (l < bcnt ? l : bcnt - 1);
        int cvec = ecol[idx];

        int c = __builtin_amdgcn_readlane(cvec, 0);
        float4 cc  = CCW4[c * 4 + j4];
        float  acv = attr[(size_t)c * 64 + l];
        float  lcv = lfp[c * 16 + l];

        for (int k = 0; k < bcnt; ++k) {
            // stage current attr row into LDS early (wait hidden under VALU below)
            Acbuf[w][l] = acv;

            // prefetch next edge
            int kn = (k + 1 < bcnt) ? k + 1 : k;
            int c2 = __builtin_amdgcn_readlane(cvec, kn);
            float4 cc_n  = CCW4[c2 * 4 + j4];
            float  ac_n  = attr[(size_t)c2 * 64 + l];
            float  lcv_n = lfp[c2 * 16 + l];

            // distance entry (lanes 0-15 authoritative, rest replicas)
            float dx = crx - cc.x, dy = cry - cc.y, dz = crz - cc.z;
            float m = __builtin_amdgcn_sqrtf(dx * dx + dy * dy + dz * dz) * cwr * cc.w;

            // broadcast M via readlane -> SGPRs (no LDS round-trip)
            float sm0 = RLF(m, 0),  sm1 = RLF(m, 1),  sm2 = RLF(m, 2),  sm3 = RLF(m, 3);
            float sm4 = RLF(m, 4),  sm5 = RLF(m, 5),  sm6 = RLF(m, 6),  sm7 = RLF(m, 7);
            float sm8 = RLF(m, 8),  sm9 = RLF(m, 9),  sm10 = RLF(m, 10), sm11 = RLF(m, 11);
            float sm12 = RLF(m, 12), sm13 = RLF(m, 13), sm14 = RLF(m, 14), sm15 = RLF(m, 15);

            // U[j] = sum_i Ar[i][a] * M[i][j]
            float Ux = fmaf(ArA3, sm12, fmaf(ArA2, sm8,  fmaf(ArA1, sm4,  ArA0 * sm0)));
            float Uy = fmaf(ArA3, sm13, fmaf(ArA2, sm9,  fmaf(ArA1, sm5,  ArA0 * sm1)));
            float Uz = fmaf(ArA3, sm14, fmaf(ArA2, sm10, fmaf(ArA1, sm6,  ArA0 * sm2)));
            float Uw = fmaf(ArA3, sm15, fmaf(ArA2, sm11, fmaf(ArA1, sm7,  ArA0 * sm3)));

            float4 A0 = *(const float4*)&Acbuf[w][b0];
            float4 A1 = *(const float4*)&Acbuf[w][16 + b0];
            float4 A2 = *(const float4*)&Acbuf[w][32 + b0];
            float4 A3 = *(const float4*)&Acbuf[w][48 + b0];
            float ex = Ux * A0.x + Uy * A1.x + Uz * A2.x + Uw * A3.x;
            float ey = Ux * A0.y + Uy * A1.y + Uz * A2.y + Uw * A3.y;
            float ez = Ux * A0.z + Uy * A1.z + Uz * A2.z + Uw * A3.z;
            float ew = Ux * A0.w + Uy * A1.w + Uz * A2.w + Uw * A3.w;

            float glf  = (lrv + lcv) * lfmask;
            float part = ex * ex + ey * ey + ez * ez + ew * ew + glf * glf;
            float tot  = wave_sum64(part);
            float invr = __builtin_amdgcn_rcpf(__builtin_amdgcn_sqrtf(tot) + 1.f);

            ax = fmaf(ex, invr, ax); ay = fmaf(ey, invr, ay);
            az = fmaf(ez, invr, az); aw = fmaf(ew, invr, aw);
            sgeo = fmaf(glf, invr, sgeo);
            invs += invr;
            sp = fmaf(lcv, pmask, sp);

            cc = cc_n; acv = ac_n; lcv = lcv_n;
        }
    }

    // per-node sums: [0..255] radial, [256..264] geo, [265..271] zero,
    // [272] invs, [273..275] pooled sums, [276] cnt
    *(float4*)&S[w][l * 4] = make_float4(ax, ay, az, aw);
    if (l < 9)       S[w][256 + l] = sgeo;
    else if (l < 16) S[w][256 + l] = 0.f;
    if (l == 16)     S[w][272] = invs;
    if (l >= 12 && l < 15) S[w][273 + (l - 12)] = sp;
    if (l == 17)     S[w][276] = (float)(en - st);
    // S is wave-private: no __syncthreads needed (program-order DS deps)

    float invsum = S[w][272];
    float acc = bvec[l] * invsum;
    const float4* WK4 = (const float4*)wk;
    #pragma unroll 4
    for (int kb = 0; kb < NKB; ++kb) {
        float4 wv = WK4[kb * 64 + l];
        float4 sv = *(const float4*)&S[w][kb * 4];
        acc += wv.x * sv.x + wv.y * sv.y + wv.z * sv.z + wv.w * sv.w;
    }
    out[(size_t)n * OUTC + l] = acc;

    float cntv = S[w][276];
    float invc = __builtin_amdgcn_rcpf(fmaxf(cntv, 1.f));
    if (l < 12) {
        int x = l % 3;
        out[(size_t)n * OUTC + 64 + l] = (cntv * coord[(size_t)n * 12 + l] - S[w][273 + x]) * invc;
    }
}

extern "C" void kernel_launch(void* const* d_in, const int* in_sizes, int n_in,
                              void* d_out, int out_size, void* d_ws, size_t ws_size,
                              hipStream_t stream) {
    const float* coord = (const float*)d_in[0];
    const float* attr  = (const float*)d_in[1];
    const float* cw    = (const float*)d_in[2];
    const float* W     = (const float*)d_in[3];
    const float* bvec  = (const float*)d_in[4];
    const int*   row   = (const int*)d_in[5];
    const int*   col   = (const int*)d_in[6];
    float* out = (float*)d_out;
    float* ws  = (float*)d_ws;
    int E = in_sizes[5];

    float* ccwp = ws + CCW_OFF;
    float* lfp  = ws + LFP_OFF;
    float* wk   = ws + WK_OFF;
    int* counts = (int*)(ws + CNT_OFF);
    int* offs   = (int*)(ws + OFFS_OFF);
    int* perm   = (int*)(ws + PERM_OFF);
    int* ecol   = (int*)(ws + ECOL_OFF);
    int* bsum   = (int*)(ws + BSUM_OFF);

    hipMemsetAsync(counts, 0, NN * sizeof(int), stream);
    prep_kernel<<<(NN + 255) / 256, 256, 0, stream>>>(coord, cw, W, ccwp, lfp, wk);
    hist_kernel<<<(E + 255) / 256, 256, 0, stream>>>(row, counts, perm, E);
    scan1_kernel<<<NB, 256, 0, stream>>>(counts, bsum);
    scan2_kernel<<<1, 256, 0, stream>>>(bsum, offs);
    scan3_kernel<<<NB, 256, 0, stream>>>(counts, bsum, offs);
    scatter_kernel<<<(E + 255) / 256, 256, 0, stream>>>(row, col, offs, perm, ecol, E);
    edge_kernel<<<NN / 4, 256, 0, stream>>>(coord, attr, bvec, ccwp, lfp, wk,
                                            offs, ecol, out);
}